// Round 2
// baseline (1023.905 us; speedup 1.0000x reference)
//
#include <hip/hip_runtime.h>
#include <cstdint>
#include <cstddef>

// ---------------------------------------------------------------------------
// MultiStageDiT round 2: adaptive-chunk workspace plan, reg-staged LDS only
// (no global_load_lds this round), attention with 64KB LDS (tiled K/V).
// ---------------------------------------------------------------------------

typedef float  f32x4    __attribute__((ext_vector_type(4)));
typedef __bf16 bf16x8_t __attribute__((ext_vector_type(8)));
typedef __bf16 bf16x4_t __attribute__((ext_vector_type(4)));

#define DEV __device__ __forceinline__

// Fragment read from a row-major LDS tile whose 16B chunks are XOR-swizzled
// by (row&7): LDS chunk lc holds global chunk lc^(row&7).
DEV bf16x8_t lds_frag(const __bf16* base, int row, int chunk, int row_elems) {
    return *(const bf16x8_t*)(base + row * row_elems + ((chunk ^ (row & 7)) << 3));
}

DEV float gelu_tanh(float v) {
    float u = 0.7978845608028654f * (v + 0.044715f * v * v * v);
    float e = __expf(2.f * u);            // overflow -> inf -> th -> 1 (correct)
    float th = 1.f - 2.f / (e + 1.f);
    return 0.5f * v * (1.f + th);
}

// window-partitioned row index (global, 0..16383) -> token row index
DEV int win2tok(int r) {
    int nb = r >> 12, wi = (r >> 8) & 15, l = r & 255;
    return (nb << 12) + (wi >> 2) * 1024 + (l >> 4) * 64 + (wi & 3) * 16 + (l & 15);
}

// ---------------------------------------------------------------------------
// prep kernels
// ---------------------------------------------------------------------------
__global__ void silu_k(const float* __restrict__ c, float* __restrict__ o, int n) {
    int i = blockIdx.x * 256 + threadIdx.x;
    if (i < n) { float v = c[i]; o[i] = v / (1.f + __expf(-v)); }
}

__global__ void zero_k(float* o, int n) {
    int i = blockIdx.x * 256 + threadIdx.x;
    if (i < n) o[i] = 0.f;
}

// mod[4][6144] = silu(c) @ adaLN_w^T + adaLN_b.  One wave per output elem.
__global__ __launch_bounds__(256)
void mod_gemv(const float* __restrict__ sc, const float* __restrict__ w,
              const float* __restrict__ b, float* __restrict__ mod) {
    int o = (blockIdx.x << 2) + (threadIdx.x >> 6);
    int lane = threadIdx.x & 63;
    int n = o / 6144, col = o % 6144;
    const float4* wr = (const float4*)(w + (size_t)col * 1024);
    const float4* sr = (const float4*)(sc + n * 1024);
    float acc = 0.f;
    #pragma unroll 4
    for (int i = lane; i < 256; i += 64) {
        float4 a = wr[i], x = sr[i];
        acc += a.x * x.x + a.y * x.y + a.z * x.z + a.w * x.w;
    }
    #pragma unroll
    for (int m = 1; m < 64; m <<= 1) acc += __shfl_xor(acc, m);
    if (lane == 0) mod[o] = acc + b[col];
}

// LN(row) -> modulate -> bf16, one block per output row (local index within
// chunk; global row = local + r0). permute=1: gather source from token row.
__global__ __launch_bounds__(256)
void ln_mod_k(const float* __restrict__ src, const float* __restrict__ mod,
              int sh_off, int sc_off, __bf16* __restrict__ out, int permute, int r0) {
    int rl = blockIdx.x;
    int r = rl + r0;
    int nb = r >> 12;
    int t = permute ? win2tok(r) : r;
    float4 v = ((const float4*)(src + (size_t)t * 1024))[threadIdx.x];
    float s  = v.x + v.y + v.z + v.w;
    float sq = v.x * v.x + v.y * v.y + v.z * v.z + v.w * v.w;
    #pragma unroll
    for (int m = 1; m < 64; m <<= 1) { s += __shfl_xor(s, m); sq += __shfl_xor(sq, m); }
    __shared__ float ps[4], pq[4];
    int wv = threadIdx.x >> 6, ln = threadIdx.x & 63;
    if (ln == 0) { ps[wv] = s; pq[wv] = sq; }
    __syncthreads();
    s  = ps[0] + ps[1] + ps[2] + ps[3];
    sq = pq[0] + pq[1] + pq[2] + pq[3];
    float mean = s * (1.f / 1024.f);
    float var  = sq * (1.f / 1024.f) - mean * mean;
    float rstd = rsqrtf(var + 1e-6f);
    int c = threadIdx.x << 2;
    const float* mrow = mod + nb * 6144;
    float4 scv = *(const float4*)(mrow + sc_off + c);
    float4 shv = *(const float4*)(mrow + sh_off + c);
    bf16x4_t o;
    o[0] = (__bf16)((v.x - mean) * rstd * (1.f + scv.x) + shv.x);
    o[1] = (__bf16)((v.y - mean) * rstd * (1.f + scv.y) + shv.y);
    o[2] = (__bf16)((v.z - mean) * rstd * (1.f + scv.z) + shv.z);
    o[3] = (__bf16)((v.w - mean) * rstd * (1.f + scv.w) + shv.w);
    *(bf16x4_t*)(out + (size_t)rl * 1024 + c) = o;
}

// ---------------------------------------------------------------------------
// bf16 GEMM  C[M,N] = A[M,K] @ Bw[N,K]^T + bias.  A bf16 (ws), Bw f32 (weights,
// converted to bf16 during LDS staging). 128x128 tile, BK=64, 4 waves (2x2),
// 16x16x32 MFMA, XOR-swizzled LDS, reg-staged ds_write_b128.
// Rows are chunk-local; r0 = global row offset of the chunk.
// EPI: 0 bf16 store | 1 win2tok scatter: x + g_msa*(v+b) f32
//      2 gelu->bf16 | 3 xo + g_mlp*(v+b) f32
// ---------------------------------------------------------------------------
template <int EPI>
__global__ __launch_bounds__(256)
void gemm_bt(const __bf16* __restrict__ A, const float* __restrict__ Bw,
             const float* __restrict__ bias, void* __restrict__ Cout,
             const float* __restrict__ extra, const float* __restrict__ mod,
             int N, int K, int r0) {
    __shared__ __align__(16) __bf16 lA[128 * 64];
    __shared__ __align__(16) __bf16 lB[128 * 64];
    const int tid = threadIdx.x, lane = tid & 63, wv = tid >> 6;
    const int wr = wv >> 1, wc = wv & 1;
    const int bm = blockIdx.y << 7, bn = blockIdx.x << 7;

    f32x4 acc[4][4];
    const f32x4 z4 = {0.f, 0.f, 0.f, 0.f};
    #pragma unroll
    for (int i = 0; i < 4; ++i)
        #pragma unroll
        for (int j = 0; j < 4; ++j) acc[i][j] = z4;

    const int srow = lane >> 3;       // sub-row staged by this lane (== rr&7)
    const int lc   = lane & 7;        // LDS chunk written
    const int gc   = lc ^ srow;       // global chunk loaded (swizzle)

    for (int k0 = 0; k0 < K; k0 += 64) {
        #pragma unroll
        for (int q = 0; q < 4; ++q) {
            int rr = (wv << 5) + (q << 3) + srow;
            *(bf16x8_t*)(lA + rr * 64 + (lc << 3)) =
                *(const bf16x8_t*)(A + (size_t)(bm + rr) * K + k0 + (gc << 3));
            const float4* bs = (const float4*)(Bw + (size_t)(bn + rr) * K + k0 + (gc << 3));
            float4 b0 = bs[0], b1 = bs[1];
            bf16x8_t bb;
            bb[0] = (__bf16)b0.x; bb[1] = (__bf16)b0.y; bb[2] = (__bf16)b0.z; bb[3] = (__bf16)b0.w;
            bb[4] = (__bf16)b1.x; bb[5] = (__bf16)b1.y; bb[6] = (__bf16)b1.z; bb[7] = (__bf16)b1.w;
            *(bf16x8_t*)(lB + rr * 64 + (lc << 3)) = bb;
        }
        __syncthreads();
        #pragma unroll
        for (int ks = 0; ks < 2; ++ks) {
            bf16x8_t af[4], bfr[4];
            #pragma unroll
            for (int i = 0; i < 4; ++i) {
                af[i]  = lds_frag(lA, (wr << 6) + (i << 4) + (lane & 15), (ks << 2) + (lane >> 4), 64);
                bfr[i] = lds_frag(lB, (wc << 6) + (i << 4) + (lane & 15), (ks << 2) + (lane >> 4), 64);
            }
            #pragma unroll
            for (int mi = 0; mi < 4; ++mi)
                #pragma unroll
                for (int ni = 0; ni < 4; ++ni)
                    acc[mi][ni] = __builtin_amdgcn_mfma_f32_16x16x32_bf16(af[mi], bfr[ni], acc[mi][ni], 0, 0, 0);
        }
        __syncthreads();
    }

    #pragma unroll
    for (int mi = 0; mi < 4; ++mi) {
        #pragma unroll
        for (int j = 0; j < 4; ++j) {
            int m = bm + (wr << 6) + (mi << 4) + ((lane >> 4) << 2) + j;   // chunk-local row
            #pragma unroll
            for (int ni = 0; ni < 4; ++ni) {
                int n = bn + (wc << 6) + (ni << 4) + (lane & 15);
                float v = acc[mi][ni][j] + bias[n];
                if constexpr (EPI == 0) {
                    ((__bf16*)Cout)[(size_t)m * N + n] = (__bf16)v;
                } else if constexpr (EPI == 1) {
                    int mg = m + r0;                       // global window row
                    int tr = win2tok(mg);                  // global token row
                    float g = mod[(mg >> 12) * 6144 + 2048 + n];
                    ((float*)Cout)[(size_t)tr * 1024 + n] = extra[(size_t)tr * 1024 + n] + g * v;
                } else if constexpr (EPI == 2) {
                    ((__bf16*)Cout)[(size_t)m * N + n] = (__bf16)gelu_tanh(v);
                } else {
                    int mg = m + r0;                       // global token row
                    float g = mod[(mg >> 12) * 6144 + 5120 + n];
                    ((float*)Cout)[(size_t)mg * 1024 + n] = extra[(size_t)mg * 1024 + n] + g * v;
                }
            }
        }
    }
}

// ---------------------------------------------------------------------------
// Fused window attention, 64KB LDS. One block (4 waves) per (window, head).
// Q fragments from global; K/V staged per 64-key tile (XOR-swizzled, V
// transposed); rel-pos bias tables Th/Tw[256][16] in LDS; online softmax.
// All row indices chunk-local.
// ---------------------------------------------------------------------------
__global__ __launch_bounds__(256)
void attn_k(const __bf16* __restrict__ qkv, const float* __restrict__ relh,
            const float* __restrict__ relw, __bf16* __restrict__ out) {
    __shared__ __align__(16) __bf16 lP[4][4096];     // per-wave 64x64 P tile
    __shared__ __align__(16) __bf16 lKt[64 * 64];    // K tile  [krow][64]
    __shared__ __align__(16) __bf16 lVt[64 * 64];    // V^T tile [d][64 kv]
    __shared__ __align__(16) __bf16 lTh[256 * 16];
    __shared__ __align__(16) __bf16 lTw[256 * 16];

    const int blk = blockIdx.x, win = blk >> 4, h = blk & 15;
    const int tid = threadIdx.x, lane = tid & 63, wv = tid >> 6;
    const __bf16* base = qkv + (size_t)win * 256 * 3072 + h * 64;

    // ---- Q fragments straight from global (L2-resident) ----
    bf16x8_t qf[4][2];
    #pragma unroll
    for (int mi = 0; mi < 4; ++mi)
        #pragma unroll
        for (int ks = 0; ks < 2; ++ks) {
            int qr = (wv << 6) + (mi << 4) + (lane & 15);
            qf[mi][ks] = *(const bf16x8_t*)(base + (size_t)qr * 3072 + (((ks << 2) + (lane >> 4)) << 3));
        }

    // ---- rel-pos bias tables: thread t handles q-row t ----
    {
        float qv[64];
        const __bf16* qrow = base + (size_t)tid * 3072;
        #pragma unroll
        for (int c8 = 0; c8 < 8; ++c8) {
            bf16x8_t q8 = *(const bf16x8_t*)(qrow + (c8 << 3));
            #pragma unroll
            for (int e = 0; e < 8; ++e) qv[c8 * 8 + e] = (float)q8[e];
        }
        int qi = tid >> 4, qj = tid & 15;
        for (int kk = 0; kk < 16; ++kk) {
            const float4* rh = (const float4*)(relh + (size_t)(qi - kk + 15) * 64);
            const float4* rw = (const float4*)(relw + (size_t)(qj - kk + 15) * 64);
            float ah = 0.f, aw = 0.f;
            #pragma unroll
            for (int c4 = 0; c4 < 16; ++c4) {
                float4 r1 = rh[c4], r2 = rw[c4];
                ah += qv[c4*4]*r1.x + qv[c4*4+1]*r1.y + qv[c4*4+2]*r1.z + qv[c4*4+3]*r1.w;
                aw += qv[c4*4]*r2.x + qv[c4*4+1]*r2.y + qv[c4*4+2]*r2.z + qv[c4*4+3]*r2.w;
            }
            lTh[tid * 16 + kk] = (__bf16)ah;
            lTw[tid * 16 + kk] = (__bf16)aw;
        }
    }
    __syncthreads();

    // ---- online softmax state ----
    const f32x4 z4 = {0.f, 0.f, 0.f, 0.f};
    f32x4 oacc[4][4];
    #pragma unroll
    for (int a = 0; a < 4; ++a)
        #pragma unroll
        for (int b = 0; b < 4; ++b) oacc[a][b] = z4;
    float mrow[4][4], lrow[4][4], twv_[4][4];
    #pragma unroll
    for (int mi = 0; mi < 4; ++mi)
        #pragma unroll
        for (int j = 0; j < 4; ++j) {
            mrow[mi][j] = -1e30f; lrow[mi][j] = 0.f;
            int qr = (wv << 6) + (mi << 4) + ((lane >> 4) << 2) + j;
            twv_[mi][j] = (float)lTw[qr * 16 + (lane & 15)];   // kj == lane&15
        }
    __bf16* lPw = lP[wv];

    for (int kt = 0; kt < 4; ++kt) {
        __syncthreads();                 // prev tile's lKt/lVt reads complete
        // ---- stage K tile + V^T tile (64 keys) ----
        #pragma unroll
        for (int q = 0; q < 2; ++q) {
            int kl = (q << 5) + (tid >> 3);      // key-local 0..63
            int lc = tid & 7, gc = lc ^ (kl & 7);
            *(bf16x8_t*)(lKt + kl * 64 + (lc << 3)) =
                *(const bf16x8_t*)(base + 1024 + (size_t)(kt * 64 + kl) * 3072 + (gc << 3));
            bf16x8_t v8 = *(const bf16x8_t*)(base + 2048 + (size_t)(kt * 64 + kl) * 3072 + (lc << 3));
            #pragma unroll
            for (int e = 0; e < 8; ++e) {
                int d = (lc << 3) + e;
                lVt[d * 64 + ((((kl >> 3) ^ (d & 7)) << 3) | (kl & 7))] = v8[e];
            }
        }
        __syncthreads();

        // ---- QK^T ----
        f32x4 s[4][4];
        #pragma unroll
        for (int a = 0; a < 4; ++a)
            #pragma unroll
            for (int b = 0; b < 4; ++b) s[a][b] = z4;
        #pragma unroll
        for (int ks = 0; ks < 2; ++ks) {
            bf16x8_t kf[4];
            #pragma unroll
            for (int ni = 0; ni < 4; ++ni)
                kf[ni] = lds_frag(lKt, (ni << 4) + (lane & 15), (ks << 2) + (lane >> 4), 64);
            #pragma unroll
            for (int mi = 0; mi < 4; ++mi)
                #pragma unroll
                for (int ni = 0; ni < 4; ++ni)
                    s[mi][ni] = __builtin_amdgcn_mfma_f32_16x16x32_bf16(qf[mi][ks], kf[ni], s[mi][ni], 0, 0, 0);
        }

        // ---- bias + online softmax + P write (wave-local) ----
        #pragma unroll
        for (int mi = 0; mi < 4; ++mi) {
            #pragma unroll
            for (int j = 0; j < 4; ++j) {
                int qr = (wv << 6) + (mi << 4) + ((lane >> 4) << 2) + j;
                bf16x4_t th4 = *(const bf16x4_t*)(lTh + qr * 16 + (kt << 2));
                float sv[4]; float vmax = -1e30f;
                #pragma unroll
                for (int ni = 0; ni < 4; ++ni) {
                    sv[ni] = s[mi][ni][j] * 0.125f + (float)th4[ni] + twv_[mi][j];
                    vmax = fmaxf(vmax, sv[ni]);
                }
                #pragma unroll
                for (int msk = 1; msk < 16; msk <<= 1) vmax = fmaxf(vmax, __shfl_xor(vmax, msk));
                float mold = mrow[mi][j], mnew = fmaxf(mold, vmax);
                float f = __expf(mold - mnew);
                float rs = 0.f;
                #pragma unroll
                for (int ni = 0; ni < 4; ++ni) { float p = __expf(sv[ni] - mnew); sv[ni] = p; rs += p; }
                #pragma unroll
                for (int msk = 1; msk < 16; msk <<= 1) rs += __shfl_xor(rs, msk);
                mrow[mi][j] = mnew;
                lrow[mi][j] = lrow[mi][j] * f + rs;
                #pragma unroll
                for (int no = 0; no < 4; ++no) oacc[mi][no][j] *= f;
                int rl = (mi << 4) + ((lane >> 4) << 2) + j;
                #pragma unroll
                for (int ni = 0; ni < 4; ++ni) {
                    int col = (ni << 4) + (lane & 15);
                    lPw[rl * 64 + ((((col >> 3) ^ (rl & 7)) << 3) | (col & 7))] = (__bf16)sv[ni];
                }
            }
        }
        __syncthreads();                 // P write -> P read ordering

        // ---- PV ----
        #pragma unroll
        for (int ks = 0; ks < 2; ++ks) {
            bf16x8_t pf[4], vf[4];
            #pragma unroll
            for (int mo = 0; mo < 4; ++mo)
                pf[mo] = lds_frag(lPw, (mo << 4) + (lane & 15), (ks << 2) + (lane >> 4), 64);
            #pragma unroll
            for (int no = 0; no < 4; ++no)
                vf[no] = lds_frag(lVt, (no << 4) + (lane & 15), (ks << 2) + (lane >> 4), 64);
            #pragma unroll
            for (int mo = 0; mo < 4; ++mo)
                #pragma unroll
                for (int no = 0; no < 4; ++no)
                    oacc[mo][no] = __builtin_amdgcn_mfma_f32_16x16x32_bf16(pf[mo], vf[no], oacc[mo][no], 0, 0, 0);
        }
    }

    // ---- normalize + write ----
    #pragma unroll
    for (int mo = 0; mo < 4; ++mo) {
        #pragma unroll
        for (int j = 0; j < 4; ++j) {
            float inv = 1.f / lrow[mo][j];
            int qr = (wv << 6) + (mo << 4) + ((lane >> 4) << 2) + j;
            #pragma unroll
            for (int no = 0; no < 4; ++no) {
                int col = (no << 4) + (lane & 15);
                out[(size_t)(win * 256 + qr) * 1024 + h * 64 + col] = (__bf16)(oacc[mo][no][j] * inv);
            }
        }
    }
}

// ---------------------------------------------------------------------------
extern "C" void kernel_launch(void* const* d_in, const int* in_sizes, int n_in,
                              void* d_out, int out_size, void* d_ws, size_t ws_size,
                              hipStream_t stream) {
    const float* x      = (const float*)d_in[0];
    const float* c      = (const float*)d_in[1];
    const float* qkv_w  = (const float*)d_in[2];
    const float* qkv_b  = (const float*)d_in[3];
    const float* proj_w = (const float*)d_in[4];
    const float* proj_b = (const float*)d_in[5];
    const float* rel_h  = (const float*)d_in[6];
    const float* rel_w  = (const float*)d_in[7];
    const float* ada_w  = (const float*)d_in[8];
    const float* ada_b  = (const float*)d_in[9];
    const float* fc1_w  = (const float*)d_in[10];
    const float* fc1_b  = (const float*)d_in[11];
    const float* fc2_w  = (const float*)d_in[12];
    const float* fc2_b  = (const float*)d_in[13];
    float* xo = (float*)d_out;

    char* ws = (char*)d_ws;
    // chunk size: bufA = CH*2KB (a_in/attn/m_in), bufB = CH*8KB (qkv/hdn)
    int CH = 0;
    const int cands[7] = {16384, 8192, 4096, 2048, 1024, 512, 256};
    for (int i = 0; i < 7; ++i)
        if ((1u << 20) + (size_t)cands[i] * 10240 <= ws_size) { CH = cands[i]; break; }
    if (CH == 0) {                        // signature: all-zero output
        zero_k<<<65536, 256, 0, stream>>>(xo, 16777216);
        return;
    }
    const int NCH = 16384 / CH;

    float*  ws_silu = (float*)(ws);                    // 16KB
    float*  ws_mod  = (float*)(ws + 65536);            // 96KB
    __bf16* bufA    = (__bf16*)(ws + (1u << 20));
    __bf16* bufB    = (__bf16*)(ws + (1u << 20) + (size_t)CH * 2048);

    silu_k  <<<16,   256, 0, stream>>>(c, ws_silu, 4096);
    mod_gemv<<<6144, 256, 0, stream>>>(ws_silu, ada_w, ada_b, ws_mod);

    // ---- MSA over chunks ----
    for (int ci = 0; ci < NCH; ++ci) {
        int r0 = ci * CH;
        ln_mod_k<<<CH, 256, 0, stream>>>(x, ws_mod, 0, 1024, bufA, 1, r0);
        gemm_bt<0><<<dim3(24, CH / 128), 256, 0, stream>>>(bufA, qkv_w, qkv_b, bufB,
                                                           nullptr, nullptr, 3072, 1024, r0);
        attn_k<<<(CH / 256) * 16, 256, 0, stream>>>(bufB, rel_h, rel_w, bufA);
        gemm_bt<1><<<dim3(8, CH / 128), 256, 0, stream>>>(bufA, proj_w, proj_b, xo,
                                                          x, ws_mod, 1024, 1024, r0);
    }
    // ---- MLP over chunks ----
    for (int ci = 0; ci < NCH; ++ci) {
        int r0 = ci * CH;
        ln_mod_k<<<CH, 256, 0, stream>>>(xo, ws_mod, 3072, 4096, bufA, 0, r0);
        gemm_bt<2><<<dim3(32, CH / 128), 256, 0, stream>>>(bufA, fc1_w, fc1_b, bufB,
                                                           nullptr, nullptr, 4096, 1024, r0);
        gemm_bt<3><<<dim3(8, CH / 128), 256, 0, stream>>>(bufB, fc2_w, fc2_b, xo,
                                                          xo, ws_mod, 1024, 4096, r0);
    }
}

// Round 3
// 832.767 us; speedup vs baseline: 1.2295x; 1.2295x over previous
//
#include <hip/hip_runtime.h>
#include <cstdint>
#include <cstddef>

// ---------------------------------------------------------------------------
// MultiStageDiT round 3: bf16 pre-converted weights + global_load_lds staging
// with single-barrier double-buffered 2-phase K-loop (T3 minimum recipe).
// Attention kernel unchanged from the passing round-2 version.
// ---------------------------------------------------------------------------

typedef float  f32x4    __attribute__((ext_vector_type(4)));
typedef __bf16 bf16x8_t __attribute__((ext_vector_type(8)));
typedef __bf16 bf16x4_t __attribute__((ext_vector_type(4)));

#define DEV __device__ __forceinline__

// global -> LDS direct copy, 16 B/lane. LDS dest is wave-uniform base; HW
// writes lane i at base + i*16 (m104/m108). Global src is per-lane (m173).
DEV void gload_lds16(const void* g, void* l) {
    auto gp = (const uint32_t __attribute__((address_space(1)))*)(uintptr_t)g;
    auto lp = (uint32_t __attribute__((address_space(3)))*)(uint32_t)(uintptr_t)l;
    __builtin_amdgcn_global_load_lds(gp, lp, 16, 0, 0);
}

// Fragment read from a row-major LDS tile whose 16B chunks are XOR-swizzled
// by (row&7): LDS chunk lc holds global chunk lc^(row&7).
DEV bf16x8_t lds_frag(const __bf16* base, int row, int chunk, int row_elems) {
    return *(const bf16x8_t*)(base + row * row_elems + ((chunk ^ (row & 7)) << 3));
}

DEV float gelu_tanh(float v) {
    float u = 0.7978845608028654f * (v + 0.044715f * v * v * v);
    float e = __expf(2.f * u);            // overflow -> inf -> th -> 1 (correct)
    float th = 1.f - 2.f / (e + 1.f);
    return 0.5f * v * (1.f + th);
}

// window-partitioned row index (global, 0..16383) -> token row index
DEV int win2tok(int r) {
    int nb = r >> 12, wi = (r >> 8) & 15, l = r & 255;
    return (nb << 12) + (wi >> 2) * 1024 + (l >> 4) * 64 + (wi & 3) * 16 + (l & 15);
}

// ---------------------------------------------------------------------------
// prep kernels
// ---------------------------------------------------------------------------
__global__ void silu_k(const float* __restrict__ c, float* __restrict__ o, int n) {
    int i = blockIdx.x * 256 + threadIdx.x;
    if (i < n) { float v = c[i]; o[i] = v / (1.f + __expf(-v)); }
}

__global__ void zero_k(float* o, int n) {
    int i = blockIdx.x * 256 + threadIdx.x;
    if (i < n) o[i] = 0.f;
}

__global__ void conv_bf16(const float* __restrict__ s, __bf16* __restrict__ d, int n4) {
    int i = blockIdx.x * 256 + threadIdx.x;
    if (i < n4) {
        float4 v = ((const float4*)s)[i];
        bf16x4_t o; o[0] = (__bf16)v.x; o[1] = (__bf16)v.y; o[2] = (__bf16)v.z; o[3] = (__bf16)v.w;
        ((bf16x4_t*)d)[i] = o;
    }
}

// mod[4][6144] = silu(c) @ adaLN_w^T + adaLN_b.  One wave per output elem.
__global__ __launch_bounds__(256)
void mod_gemv(const float* __restrict__ sc, const float* __restrict__ w,
              const float* __restrict__ b, float* __restrict__ mod) {
    int o = (blockIdx.x << 2) + (threadIdx.x >> 6);
    int lane = threadIdx.x & 63;
    int n = o / 6144, col = o % 6144;
    const float4* wr = (const float4*)(w + (size_t)col * 1024);
    const float4* sr = (const float4*)(sc + n * 1024);
    float acc = 0.f;
    #pragma unroll 4
    for (int i = lane; i < 256; i += 64) {
        float4 a = wr[i], x = sr[i];
        acc += a.x * x.x + a.y * x.y + a.z * x.z + a.w * x.w;
    }
    #pragma unroll
    for (int m = 1; m < 64; m <<= 1) acc += __shfl_xor(acc, m);
    if (lane == 0) mod[o] = acc + b[col];
}

// LN(row) -> modulate -> bf16, one block per output row (chunk-local index;
// global row = local + r0). permute=1: gather source from token row.
__global__ __launch_bounds__(256)
void ln_mod_k(const float* __restrict__ src, const float* __restrict__ mod,
              int sh_off, int sc_off, __bf16* __restrict__ out, int permute, int r0) {
    int rl = blockIdx.x;
    int r = rl + r0;
    int nb = r >> 12;
    int t = permute ? win2tok(r) : r;
    float4 v = ((const float4*)(src + (size_t)t * 1024))[threadIdx.x];
    float s  = v.x + v.y + v.z + v.w;
    float sq = v.x * v.x + v.y * v.y + v.z * v.z + v.w * v.w;
    #pragma unroll
    for (int m = 1; m < 64; m <<= 1) { s += __shfl_xor(s, m); sq += __shfl_xor(sq, m); }
    __shared__ float ps[4], pq[4];
    int wv = threadIdx.x >> 6, ln = threadIdx.x & 63;
    if (ln == 0) { ps[wv] = s; pq[wv] = sq; }
    __syncthreads();
    s  = ps[0] + ps[1] + ps[2] + ps[3];
    sq = pq[0] + pq[1] + pq[2] + pq[3];
    float mean = s * (1.f / 1024.f);
    float var  = sq * (1.f / 1024.f) - mean * mean;
    float rstd = rsqrtf(var + 1e-6f);
    int c = threadIdx.x << 2;
    const float* mrow = mod + nb * 6144;
    float4 scv = *(const float4*)(mrow + sc_off + c);
    float4 shv = *(const float4*)(mrow + sh_off + c);
    bf16x4_t o;
    o[0] = (__bf16)((v.x - mean) * rstd * (1.f + scv.x) + shv.x);
    o[1] = (__bf16)((v.y - mean) * rstd * (1.f + scv.y) + shv.y);
    o[2] = (__bf16)((v.z - mean) * rstd * (1.f + scv.z) + shv.z);
    o[3] = (__bf16)((v.w - mean) * rstd * (1.f + scv.w) + shv.w);
    *(bf16x4_t*)(out + (size_t)rl * 1024 + c) = o;
}

// ---------------------------------------------------------------------------
// bf16 GEMM  C[M,N] = A[M,K] @ B[N,K]^T + bias.  Both operands bf16.
// 128x128 tile, BK=64, 4 waves (2x2), 16x16x32 MFMA.
// global_load_lds width-16 staging into double-buffered XOR-swizzled LDS;
// single barrier per K-step (2-phase: stage t+1 issued before compute t).
// EPI: 0 bf16 store | 1 win2tok scatter: x + g_msa*(v+b) f32
//      2 gelu->bf16 | 3 xo + g_mlp*(v+b) f32
// ---------------------------------------------------------------------------
template <int EPI>
__global__ __launch_bounds__(256)
void gemm_bt(const __bf16* __restrict__ A, const __bf16* __restrict__ B,
             const float* __restrict__ bias, void* __restrict__ Cout,
             const float* __restrict__ extra, const float* __restrict__ mod,
             int N, int K, int r0) {
    __shared__ __align__(16) __bf16 lA[2][128 * 64];
    __shared__ __align__(16) __bf16 lB[2][128 * 64];
    const int tid = threadIdx.x, lane = tid & 63, wv = tid >> 6;
    const int wr = wv >> 1, wc = wv & 1;
    const int bm = blockIdx.y << 7, bn = blockIdx.x << 7;

    f32x4 acc[4][4];
    const f32x4 z4 = {0.f, 0.f, 0.f, 0.f};
    #pragma unroll
    for (int i = 0; i < 4; ++i)
        #pragma unroll
        for (int j = 0; j < 4; ++j) acc[i][j] = z4;

    const int srow = lane >> 3;       // sub-row staged by this lane (== row&7)
    const int gc   = (lane & 7) ^ srow;  // pre-swizzled global chunk (rule #21)
    const size_t arow = (size_t)(bm + srow) * K + (gc << 3);
    const size_t brow = (size_t)(bn + srow) * K + (gc << 3);

    const int nt = K >> 6;
    int cur = 0;
    // prologue: stage tile 0 into buf 0
    #pragma unroll
    for (int q = 0; q < 4; ++q) {
        int rr = (wv << 5) + (q << 3);
        gload_lds16(A + arow + (size_t)rr * K, &lA[0][rr * 64]);
        gload_lds16(B + brow + (size_t)rr * K, &lB[0][rr * 64]);
    }

    for (int t = 0; t < nt; ++t) {
        __syncthreads();              // buf[cur] staged; buf[cur^1] reads drained
        if (t + 1 < nt) {
            const size_t k1 = (size_t)(t + 1) << 6;
            #pragma unroll
            for (int q = 0; q < 4; ++q) {
                int rr = (wv << 5) + (q << 3);
                gload_lds16(A + arow + (size_t)rr * K + k1, &lA[cur ^ 1][rr * 64]);
                gload_lds16(B + brow + (size_t)rr * K + k1, &lB[cur ^ 1][rr * 64]);
            }
        }
        #pragma unroll
        for (int ks = 0; ks < 2; ++ks) {
            bf16x8_t af[4], bfr[4];
            #pragma unroll
            for (int i = 0; i < 4; ++i) {
                af[i]  = lds_frag(lA[cur], (wr << 6) + (i << 4) + (lane & 15), (ks << 2) + (lane >> 4), 64);
                bfr[i] = lds_frag(lB[cur], (wc << 6) + (i << 4) + (lane & 15), (ks << 2) + (lane >> 4), 64);
            }
            #pragma unroll
            for (int mi = 0; mi < 4; ++mi)
                #pragma unroll
                for (int ni = 0; ni < 4; ++ni)
                    acc[mi][ni] = __builtin_amdgcn_mfma_f32_16x16x32_bf16(af[mi], bfr[ni], acc[mi][ni], 0, 0, 0);
        }
        cur ^= 1;
    }

    #pragma unroll
    for (int mi = 0; mi < 4; ++mi) {
        #pragma unroll
        for (int j = 0; j < 4; ++j) {
            int m = bm + (wr << 6) + (mi << 4) + ((lane >> 4) << 2) + j;   // chunk-local row
            #pragma unroll
            for (int ni = 0; ni < 4; ++ni) {
                int n = bn + (wc << 6) + (ni << 4) + (lane & 15);
                float v = acc[mi][ni][j] + bias[n];
                if constexpr (EPI == 0) {
                    ((__bf16*)Cout)[(size_t)m * N + n] = (__bf16)v;
                } else if constexpr (EPI == 1) {
                    int mg = m + r0;
                    int tr = win2tok(mg);
                    float g = mod[(mg >> 12) * 6144 + 2048 + n];
                    ((float*)Cout)[(size_t)tr * 1024 + n] = extra[(size_t)tr * 1024 + n] + g * v;
                } else if constexpr (EPI == 2) {
                    ((__bf16*)Cout)[(size_t)m * N + n] = (__bf16)gelu_tanh(v);
                } else {
                    int mg = m + r0;
                    float g = mod[(mg >> 12) * 6144 + 5120 + n];
                    ((float*)Cout)[(size_t)mg * 1024 + n] = extra[(size_t)mg * 1024 + n] + g * v;
                }
            }
        }
    }
}

// ---------------------------------------------------------------------------
// Fused window attention (unchanged from passing round 2). One block (4 waves)
// per (window, head); K/V staged per 64-key tile; online softmax; rel-pos
// bias tables Th/Tw[256][16] in LDS.
// ---------------------------------------------------------------------------
__global__ __launch_bounds__(256)
void attn_k(const __bf16* __restrict__ qkv, const float* __restrict__ relh,
            const float* __restrict__ relw, __bf16* __restrict__ out) {
    __shared__ __align__(16) __bf16 lP[4][4096];
    __shared__ __align__(16) __bf16 lKt[64 * 64];
    __shared__ __align__(16) __bf16 lVt[64 * 64];
    __shared__ __align__(16) __bf16 lTh[256 * 16];
    __shared__ __align__(16) __bf16 lTw[256 * 16];

    const int blk = blockIdx.x, win = blk >> 4, h = blk & 15;
    const int tid = threadIdx.x, lane = tid & 63, wv = tid >> 6;
    const __bf16* base = qkv + (size_t)win * 256 * 3072 + h * 64;

    bf16x8_t qf[4][2];
    #pragma unroll
    for (int mi = 0; mi < 4; ++mi)
        #pragma unroll
        for (int ks = 0; ks < 2; ++ks) {
            int qr = (wv << 6) + (mi << 4) + (lane & 15);
            qf[mi][ks] = *(const bf16x8_t*)(base + (size_t)qr * 3072 + (((ks << 2) + (lane >> 4)) << 3));
        }

    {
        float qv[64];
        const __bf16* qrow = base + (size_t)tid * 3072;
        #pragma unroll
        for (int c8 = 0; c8 < 8; ++c8) {
            bf16x8_t q8 = *(const bf16x8_t*)(qrow + (c8 << 3));
            #pragma unroll
            for (int e = 0; e < 8; ++e) qv[c8 * 8 + e] = (float)q8[e];
        }
        int qi = tid >> 4, qj = tid & 15;
        for (int kk = 0; kk < 16; ++kk) {
            const float4* rh = (const float4*)(relh + (size_t)(qi - kk + 15) * 64);
            const float4* rw = (const float4*)(relw + (size_t)(qj - kk + 15) * 64);
            float ah = 0.f, aw = 0.f;
            #pragma unroll
            for (int c4 = 0; c4 < 16; ++c4) {
                float4 r1 = rh[c4], r2 = rw[c4];
                ah += qv[c4*4]*r1.x + qv[c4*4+1]*r1.y + qv[c4*4+2]*r1.z + qv[c4*4+3]*r1.w;
                aw += qv[c4*4]*r2.x + qv[c4*4+1]*r2.y + qv[c4*4+2]*r2.z + qv[c4*4+3]*r2.w;
            }
            lTh[tid * 16 + kk] = (__bf16)ah;
            lTw[tid * 16 + kk] = (__bf16)aw;
        }
    }
    __syncthreads();

    const f32x4 z4 = {0.f, 0.f, 0.f, 0.f};
    f32x4 oacc[4][4];
    #pragma unroll
    for (int a = 0; a < 4; ++a)
        #pragma unroll
        for (int b = 0; b < 4; ++b) oacc[a][b] = z4;
    float mrow[4][4], lrow[4][4], twv_[4][4];
    #pragma unroll
    for (int mi = 0; mi < 4; ++mi)
        #pragma unroll
        for (int j = 0; j < 4; ++j) {
            mrow[mi][j] = -1e30f; lrow[mi][j] = 0.f;
            int qr = (wv << 6) + (mi << 4) + ((lane >> 4) << 2) + j;
            twv_[mi][j] = (float)lTw[qr * 16 + (lane & 15)];
        }
    __bf16* lPw = lP[wv];

    for (int kt = 0; kt < 4; ++kt) {
        __syncthreads();
        #pragma unroll
        for (int q = 0; q < 2; ++q) {
            int kl = (q << 5) + (tid >> 3);
            int lc = tid & 7, gc = lc ^ (kl & 7);
            *(bf16x8_t*)(lKt + kl * 64 + (lc << 3)) =
                *(const bf16x8_t*)(base + 1024 + (size_t)(kt * 64 + kl) * 3072 + (gc << 3));
            bf16x8_t v8 = *(const bf16x8_t*)(base + 2048 + (size_t)(kt * 64 + kl) * 3072 + (lc << 3));
            #pragma unroll
            for (int e = 0; e < 8; ++e) {
                int d = (lc << 3) + e;
                lVt[d * 64 + ((((kl >> 3) ^ (d & 7)) << 3) | (kl & 7))] = v8[e];
            }
        }
        __syncthreads();

        f32x4 s[4][4];
        #pragma unroll
        for (int a = 0; a < 4; ++a)
            #pragma unroll
            for (int b = 0; b < 4; ++b) s[a][b] = z4;
        #pragma unroll
        for (int ks = 0; ks < 2; ++ks) {
            bf16x8_t kf[4];
            #pragma unroll
            for (int ni = 0; ni < 4; ++ni)
                kf[ni] = lds_frag(lKt, (ni << 4) + (lane & 15), (ks << 2) + (lane >> 4), 64);
            #pragma unroll
            for (int mi = 0; mi < 4; ++mi)
                #pragma unroll
                for (int ni = 0; ni < 4; ++ni)
                    s[mi][ni] = __builtin_amdgcn_mfma_f32_16x16x32_bf16(qf[mi][ks], kf[ni], s[mi][ni], 0, 0, 0);
        }

        #pragma unroll
        for (int mi = 0; mi < 4; ++mi) {
            #pragma unroll
            for (int j = 0; j < 4; ++j) {
                int qr = (wv << 6) + (mi << 4) + ((lane >> 4) << 2) + j;
                bf16x4_t th4 = *(const bf16x4_t*)(lTh + qr * 16 + (kt << 2));
                float sv[4]; float vmax = -1e30f;
                #pragma unroll
                for (int ni = 0; ni < 4; ++ni) {
                    sv[ni] = s[mi][ni][j] * 0.125f + (float)th4[ni] + twv_[mi][j];
                    vmax = fmaxf(vmax, sv[ni]);
                }
                #pragma unroll
                for (int msk = 1; msk < 16; msk <<= 1) vmax = fmaxf(vmax, __shfl_xor(vmax, msk));
                float mold = mrow[mi][j], mnew = fmaxf(mold, vmax);
                float f = __expf(mold - mnew);
                float rs = 0.f;
                #pragma unroll
                for (int ni = 0; ni < 4; ++ni) { float p = __expf(sv[ni] - mnew); sv[ni] = p; rs += p; }
                #pragma unroll
                for (int msk = 1; msk < 16; msk <<= 1) rs += __shfl_xor(rs, msk);
                mrow[mi][j] = mnew;
                lrow[mi][j] = lrow[mi][j] * f + rs;
                #pragma unroll
                for (int no = 0; no < 4; ++no) oacc[mi][no][j] *= f;
                int rl = (mi << 4) + ((lane >> 4) << 2) + j;
                #pragma unroll
                for (int ni = 0; ni < 4; ++ni) {
                    int col = (ni << 4) + (lane & 15);
                    lPw[rl * 64 + ((((col >> 3) ^ (rl & 7)) << 3) | (col & 7))] = (__bf16)sv[ni];
                }
            }
        }
        __syncthreads();

        #pragma unroll
        for (int ks = 0; ks < 2; ++ks) {
            bf16x8_t pf[4], vf[4];
            #pragma unroll
            for (int mo = 0; mo < 4; ++mo)
                pf[mo] = lds_frag(lPw, (mo << 4) + (lane & 15), (ks << 2) + (lane >> 4), 64);
            #pragma unroll
            for (int no = 0; no < 4; ++no)
                vf[no] = lds_frag(lVt, (no << 4) + (lane & 15), (ks << 2) + (lane >> 4), 64);
            #pragma unroll
            for (int mo = 0; mo < 4; ++mo)
                #pragma unroll
                for (int no = 0; no < 4; ++no)
                    oacc[mo][no] = __builtin_amdgcn_mfma_f32_16x16x32_bf16(pf[mo], vf[no], oacc[mo][no], 0, 0, 0);
        }
    }

    #pragma unroll
    for (int mo = 0; mo < 4; ++mo) {
        #pragma unroll
        for (int j = 0; j < 4; ++j) {
            float inv = 1.f / lrow[mo][j];
            int qr = (wv << 6) + (mo << 4) + ((lane >> 4) << 2) + j;
            #pragma unroll
            for (int no = 0; no < 4; ++no) {
                int col = (no << 4) + (lane & 15);
                out[(size_t)(win * 256 + qr) * 1024 + h * 64 + col] = (__bf16)(oacc[mo][no][j] * inv);
            }
        }
    }
}

// ---------------------------------------------------------------------------
extern "C" void kernel_launch(void* const* d_in, const int* in_sizes, int n_in,
                              void* d_out, int out_size, void* d_ws, size_t ws_size,
                              hipStream_t stream) {
    const float* x      = (const float*)d_in[0];
    const float* c      = (const float*)d_in[1];
    const float* qkv_w  = (const float*)d_in[2];
    const float* qkv_b  = (const float*)d_in[3];
    const float* proj_w = (const float*)d_in[4];
    const float* proj_b = (const float*)d_in[5];
    const float* rel_h  = (const float*)d_in[6];
    const float* rel_w  = (const float*)d_in[7];
    const float* ada_w  = (const float*)d_in[8];
    const float* ada_b  = (const float*)d_in[9];
    const float* fc1_w  = (const float*)d_in[10];
    const float* fc1_b  = (const float*)d_in[11];
    const float* fc2_w  = (const float*)d_in[12];
    const float* fc2_b  = (const float*)d_in[13];
    float* xo = (float*)d_out;

    char* ws = (char*)d_ws;
    const size_t MB = 1ull << 20;
    // layout: [0,160KB) scalars | [1MB,25MB) bf16 weights | [26MB,...) bufs
    int CH = 0;
    const int cands[7] = {16384, 8192, 4096, 2048, 1024, 512, 256};
    for (int i = 0; i < 7; ++i)
        if (26 * MB + (size_t)cands[i] * 10240 <= ws_size) { CH = cands[i]; break; }
    if (CH == 0) {                        // signature: all-zero output
        zero_k<<<65536, 256, 0, stream>>>(xo, 16777216);
        return;
    }
    const int NCH = 16384 / CH;

    float*  ws_silu = (float*)(ws);
    float*  ws_mod  = (float*)(ws + 65536);
    __bf16* w_qkv   = (__bf16*)(ws + 1 * MB);
    __bf16* w_proj  = (__bf16*)(ws + 7 * MB);
    __bf16* w_fc1   = (__bf16*)(ws + 9 * MB);
    __bf16* w_fc2   = (__bf16*)(ws + 17 * MB);
    __bf16* bufA    = (__bf16*)(ws + 26 * MB);
    __bf16* bufB    = (__bf16*)(ws + 26 * MB + (size_t)CH * 2048);

    silu_k   <<<16,   256, 0, stream>>>(c, ws_silu, 4096);
    mod_gemv <<<6144, 256, 0, stream>>>(ws_silu, ada_w, ada_b, ws_mod);
    conv_bf16<<<3072, 256, 0, stream>>>(qkv_w,  w_qkv,  786432);
    conv_bf16<<<1024, 256, 0, stream>>>(proj_w, w_proj, 262144);
    conv_bf16<<<4096, 256, 0, stream>>>(fc1_w,  w_fc1,  1048576);
    conv_bf16<<<4096, 256, 0, stream>>>(fc2_w,  w_fc2,  1048576);

    // ---- MSA over chunks ----
    for (int ci = 0; ci < NCH; ++ci) {
        int r0 = ci * CH;
        ln_mod_k<<<CH, 256, 0, stream>>>(x, ws_mod, 0, 1024, bufA, 1, r0);
        gemm_bt<0><<<dim3(24, CH / 128), 256, 0, stream>>>(bufA, w_qkv, qkv_b, bufB,
                                                           nullptr, nullptr, 3072, 1024, r0);
        attn_k<<<(CH / 256) * 16, 256, 0, stream>>>(bufB, rel_h, rel_w, bufA);
        gemm_bt<1><<<dim3(8, CH / 128), 256, 0, stream>>>(bufA, w_proj, proj_b, xo,
                                                          x, ws_mod, 1024, 1024, r0);
    }
    // ---- MLP over chunks ----
    for (int ci = 0; ci < NCH; ++ci) {
        int r0 = ci * CH;
        ln_mod_k<<<CH, 256, 0, stream>>>(xo, ws_mod, 3072, 4096, bufA, 0, r0);
        gemm_bt<2><<<dim3(32, CH / 128), 256, 0, stream>>>(bufA, w_fc1, fc1_b, bufB,
                                                           nullptr, nullptr, 4096, 1024, r0);
        gemm_bt<3><<<dim3(8, CH / 128), 256, 0, stream>>>(bufB, w_fc2, fc2_b, xo,
                                                          xo, ws_mod, 1024, 4096, r0);
    }
}